// Round 1
// 215.159 us; speedup vs baseline: 1.0174x; 1.0174x over previous
//
#include <hip/hip_runtime.h>

// GraphSAGE 2-layer + edge scorer, MI355X.
// R17: chunk-private binning + fused binsort/gather1.
//  - convbin's bin section now writes its 4096 records bucket-grouped and
//    CONTIGUOUS at creg[cb*RPB] plus a per-(bucket,chunk) count/offset
//    matrix (cntM/offM, 196x196). No global cursors -> hipMemsetAsync node
//    deleted; no CAP-padded creg; coalesced record write.
//  - bucket_kernel (196 blocks x 1024 thr) fuses binsort + gather1: pulls
//    the bucket's record segments from all 196 chunks into LDS, builds the
//    per-node lists in LDS (lsrc), writes csr coalesced for gather2, and
//    gathers neighbor features straight from LDS ids (no csr round-trip).
// 8 dispatches -> 6. Kept: u32 records, 8-edge-ILP gather, B-in-regs GEMMs,
// wp-dot commute (scalar gather2), mean(h1[src])@W2n == mean((h1@W2n)[src]).

#define NN 50000
#define EM 800000
#define EPOS 200000
#define ENEG 200000
#define NB 196            // coarse buckets: 196*256 >= NN
#define CAP 8192          // csr slots per bucket (max bucket ~4400 expected)
#define RPB 4096          // records per bin chunk
#define CBLK 196          // bin chunks: 196*4096 >= EM
#define MTILES 3125       // 50000 / 16 exactly
#define GEMM_GRID 512
#define XCONV 6250        // NN*128/4/256
#define BT 1024           // bucket_kernel threads

typedef __bf16 bf16;
typedef bf16 bf16x4 __attribute__((ext_vector_type(4)));
typedef bf16 bf16x8 __attribute__((ext_vector_type(8)));
typedef float floatx4 __attribute__((ext_vector_type(4)));

// ---- workspace offsets ----
// int-word offsets:
#define I_CNT  0             // NB*CBLK = 38416
#define I_OFF  38416         // 38416 -> ends 76832
#define I_ROW  76832         // 50176
#define I_REND 127008        // 50176 -> ends 177184
#define I_CSR  177184        // NB*CAP = 1,605,632 -> ends 1,782,816 (byte 7,131,264)
// byte offsets (16B-aligned):
#define B_CREG 7131264       // EM*4 = 3,200,000 -> ends 10,331,264
#define B_XB   10331264      // 12.8 MB -> ends 23,131,264
#define B_AGG1 23131264      // 12.8 MB -> ends 35,931,264
#define B_H1   35931264      // 25.6 MB -> ends 61,531,264
#define B_NV   61531264      // 800 KB -> ends 62,331,264
#define B_WT1  62331264      // 128 KB
#define B_WT2  62462336      // 128 KB
#define B_P    62593408      // 200 KB
#define B_Q    62793408      // 200 KB -> ends 62,993,408

// one grid, three independent sections: x->bf16, weights->Wt1/Wt2, bin.
__global__ __launch_bounds__(256) void convbin_kernel(
    const float* __restrict__ x, bf16* __restrict__ xb,
    const float* __restrict__ W1s, const float* __restrict__ W1n,
    const float* __restrict__ W2n, const float* __restrict__ W2s,
    bf16* __restrict__ Wt1, bf16* __restrict__ Wt2,
    const int* __restrict__ msrc, const int* __restrict__ mdst,
    unsigned* __restrict__ creg, int* __restrict__ cntM,
    int* __restrict__ offM) {
    if (blockIdx.x < XCONV) {
        int i = blockIdx.x * 256 + threadIdx.x;
        float4 v = ((const float4*)x)[i];
        bf16x4 o;
        o[0] = (bf16)v.x; o[1] = (bf16)v.y; o[2] = (bf16)v.z; o[3] = (bf16)v.w;
        *(bf16x4*)(xb + (size_t)i * 4) = o;
    } else if (blockIdx.x < XCONV + 256) {
        int i = (blockIdx.x - XCONV) * 256 + threadIdx.x;
        int n = i >> 8, k = i & 255;
        float w1 = (k < 128) ? W1s[k * 256 + n] : W1n[(k - 128) * 256 + n];
        Wt1[i] = (bf16)w1;
        float w2 = (n < 128) ? W2n[k * 128 + n] : W2s[k * 128 + (n - 128)];
        Wt2[i] = (bf16)w2;
    } else {
        // bin chunk: LDS-sort RPB edges by dst>>8, write bucket-grouped u32
        // records ((dst&255)<<16 | src) CONTIGUOUS at creg[cb*RPB], plus
        // per-(bucket,chunk) count and in-chunk offset. No global cursors.
        __shared__ int hist[NB];
        __shared__ int cnt2[NB];
        __shared__ int base[256];
        __shared__ unsigned sorted[RPB];
        int t = threadIdx.x;
        int cb = blockIdx.x - (XCONV + 256);
        int e0 = cb * RPB;
        int nrec = EM - e0; if (nrec > RPB) nrec = RPB;

        for (int i = t; i < NB; i += 256) { hist[i] = 0; cnt2[i] = 0; }
        __syncthreads();

        int myb[16];
        unsigned myrec[16];
#pragma unroll
        for (int j = 0; j < 16; ++j) {
            int idx = j * 256 + t;
            if (idx < nrec) {
                int s = msrc[e0 + idx], d = mdst[e0 + idx];
                myb[j] = d >> 8;
                myrec[j] = ((unsigned)(d & 255) << 16) | (unsigned)s;
                atomicAdd(&hist[myb[j]], 1);
            } else myb[j] = -1;
        }
        __syncthreads();

        base[t] = (t < NB) ? hist[t] : 0;
        __syncthreads();
        for (int o = 1; o < 256; o <<= 1) {
            int u = (t >= o) ? base[t - o] : 0;
            __syncthreads();
            base[t] += u;
            __syncthreads();
        }

#pragma unroll
        for (int j = 0; j < 16; ++j) {
            if (myb[j] >= 0) {
                int rk = atomicAdd(&cnt2[myb[j]], 1);
                int slot = base[myb[j]] - hist[myb[j]] + rk;
                sorted[slot] = myrec[j];
            }
        }
        __syncthreads();

        if (t < NB) {
            cntM[t * CBLK + cb] = hist[t];
            offM[t * CBLK + cb] = base[t] - hist[t];
        }
#pragma unroll
        for (int j = 0; j < 16; ++j) {
            int idx = j * 256 + t;
            if (idx < nrec) creg[(size_t)cb * RPB + idx] = sorted[idx];
        }
    }
}

// one block per bucket, 1024 threads (16 waves). Fuses binsort + gather1:
// pull the bucket's segments from all chunks into LDS, per-node scatter in
// LDS, coalesced csr write for gather2, then gather features from LDS ids.
__global__ __launch_bounds__(1024) void bucket_kernel(
    const unsigned* __restrict__ creg, const int* __restrict__ cntM,
    const int* __restrict__ offM, int* __restrict__ rowstart,
    int* __restrict__ rowend, int* __restrict__ csr,
    const bf16* __restrict__ feat, bf16* __restrict__ agg) {
    __shared__ unsigned lrec[CAP];   // raw records, chunk-concatenated
    __shared__ unsigned lsrc[CAP];   // srcs grouped by node
    __shared__ int ccnt[256];        // per-chunk count for this bucket
    __shared__ int cpos[256];        // inclusive scan of ccnt
    __shared__ int coff[256];        // in-chunk offset of this bucket's group
    __shared__ int lhist[256];       // per-node count
    __shared__ int sc[256];          // inclusive scan of lhist
    __shared__ int lcur[256];
    int b = blockIdx.x, t = threadIdx.x;

    if (t < 256) {
        int cc = 0, oo = 0;
        if (t < CBLK) { cc = cntM[b * CBLK + t]; oo = offM[b * CBLK + t]; }
        ccnt[t] = cc; cpos[t] = cc; coff[t] = oo; lhist[t] = 0;
    }
    __syncthreads();
    for (int o = 1; o < 256; o <<= 1) {
        int u = (t < 256 && t >= o) ? cpos[t - o] : 0;
        __syncthreads();
        if (t < 256) cpos[t] += u;
        __syncthreads();
    }

    int wid = t >> 6, lane = t & 63;
    // pull segments into LDS + per-node histogram
    for (int cb = wid; cb < CBLK; cb += 16) {
        int c = ccnt[cb], ofs = coff[cb], d0 = cpos[cb] - c;
        for (int i = lane; i < c; i += 64) {
            unsigned rec = creg[(size_t)cb * RPB + ofs + i];
            lrec[d0 + i] = rec;
            atomicAdd(&lhist[(int)(rec >> 16) & 255], 1);
        }
    }
    __syncthreads();
    int cntb = cpos[255];

    if (t < 256) sc[t] = lhist[t];
    __syncthreads();
    for (int o = 1; o < 256; o <<= 1) {
        int u = (t < 256 && t >= o) ? sc[t - o] : 0;
        __syncthreads();
        if (t < 256) sc[t] += u;
        __syncthreads();
    }
    if (t < 256) {
        int node = b * 256 + t;
        if (node < NN) {
            rowstart[node] = b * CAP + sc[t] - lhist[t];
            rowend[node] = b * CAP + sc[t];
        }
        lcur[t] = sc[t] - lhist[t];
    }
    __syncthreads();

    // per-node scatter in LDS
    for (int i = t; i < cntb; i += BT) {
        unsigned rec = lrec[i];
        int slot = atomicAdd(&lcur[(int)(rec >> 16) & 255], 1);
        lsrc[slot] = rec & 0xffffu;
    }
    __syncthreads();
    // coalesced csr write (consumed only by gather2)
    for (int i = t; i < cntb; i += BT) csr[b * CAP + i] = (int)lsrc[i];

    // gather: wave wid handles 16 consecutive local nodes; within a wave,
    // 16 lanes cover one feature row, 4 quads x 2 chains = 8 edges in flight.
    int q = lane >> 4, r = lane & 15;
    int cch = r * 8;
    for (int k = 0; k < 16; ++k) {
        int ln = wid * 16 + k;
        int node = b * 256 + ln;
        if (node >= NN) break;
        int beg = sc[ln] - lhist[ln], end = sc[ln];
        float acc[8] = {0.f, 0.f, 0.f, 0.f, 0.f, 0.f, 0.f, 0.f};
        float acc2[8] = {0.f, 0.f, 0.f, 0.f, 0.f, 0.f, 0.f, 0.f};
        int i = beg + q;
        for (; i + 4 < end; i += 8) {
            int s0 = (int)lsrc[i], s1 = (int)lsrc[i + 4];
            bf16x8 v0 = *(const bf16x8*)(feat + (size_t)s0 * 128 + cch);
            bf16x8 v1 = *(const bf16x8*)(feat + (size_t)s1 * 128 + cch);
#pragma unroll
            for (int u = 0; u < 8; ++u) {
                acc[u] += (float)v0[u];
                acc2[u] += (float)v1[u];
            }
        }
        if (i < end) {
            int s0 = (int)lsrc[i];
            bf16x8 v0 = *(const bf16x8*)(feat + (size_t)s0 * 128 + cch);
#pragma unroll
            for (int u = 0; u < 8; ++u) acc[u] += (float)v0[u];
        }
#pragma unroll
        for (int u = 0; u < 8; ++u) acc[u] += acc2[u];
#pragma unroll
        for (int m = 16; m <= 32; m <<= 1)
#pragma unroll
            for (int u = 0; u < 8; ++u) acc[u] += __shfl_xor(acc[u], m);
        if (q == 0) {
            int deg = end - beg;
            float inv = 1.0f / (float)(deg > 0 ? deg : 1);
            bf16x8 o;
#pragma unroll
            for (int u = 0; u < 8; ++u) o[u] = (bf16)(acc[u] * inv);
            *(bf16x8*)(agg + (size_t)node * 128 + cch) = o;
        }
    }
}

// h1 = relu([xb | agg1b] @ Wt1^T + b1) -> bf16. B in registers, A streamed.
__global__ __launch_bounds__(256) void gemm1_kernel(
    const bf16* __restrict__ xb, const bf16* __restrict__ aggb,
    const bf16* __restrict__ Wt, const float* __restrict__ b1,
    bf16* __restrict__ h1b) {
    int w = threadIdx.x >> 6;
    int lane = threadIdx.x & 63;
    int r = lane & 15, quad = lane >> 4;
    int colbase = w * 64;

    bf16x8 bfr[4][8];
#pragma unroll
    for (int t = 0; t < 4; ++t)
#pragma unroll
        for (int kk = 0; kk < 8; ++kk)
            bfr[t][kk] = *(const bf16x8*)(Wt + (size_t)(colbase + t * 16 + r) * 256
                                          + kk * 32 + quad * 8);
    float bb[4];
#pragma unroll
    for (int t = 0; t < 4; ++t) bb[t] = b1[colbase + t * 16 + r];

    for (int tile = blockIdx.x; tile < MTILES; tile += GEMM_GRID) {
        int m0 = tile * 16;
        int row = m0 + r;
        bf16x8 a[8];
#pragma unroll
        for (int kk = 0; kk < 4; ++kk)
            a[kk] = *(const bf16x8*)(xb + (size_t)row * 128 + kk * 32 + quad * 8);
#pragma unroll
        for (int kk = 4; kk < 8; ++kk)
            a[kk] = *(const bf16x8*)(aggb + (size_t)row * 128 + (kk - 4) * 32 + quad * 8);
        floatx4 acc[4];
#pragma unroll
        for (int t = 0; t < 4; ++t) acc[t] = (floatx4){0.f, 0.f, 0.f, 0.f};
#pragma unroll
        for (int kk = 0; kk < 8; ++kk)
#pragma unroll
            for (int t = 0; t < 4; ++t)
                acc[t] = __builtin_amdgcn_mfma_f32_16x16x32_bf16(a[kk], bfr[t][kk],
                                                                 acc[t], 0, 0, 0);
        int mb = m0 + quad * 4;
#pragma unroll
        for (int t = 0; t < 4; ++t) {
            int col = colbase + t * 16 + r;
#pragma unroll
            for (int rr = 0; rr < 4; ++rr) {
                float v = acc[t][rr] + bb[t];
                v = v > 0.f ? v : 0.f;
                h1b[(size_t)(mb + rr) * 256 + col] = (bf16)v;
            }
        }
    }
}

// Fused gemm2: nodev[n] = {zp, zq, ps, qs}; zp=(h1@W2n)[n].wp[:128] etc.
__global__ __launch_bounds__(256) void gemm2_kernel(
    const bf16* __restrict__ h1b, const bf16* __restrict__ Wt,
    const float* __restrict__ b2, const float* __restrict__ wp,
    float4* __restrict__ nodev) {
    __shared__ float lp[4][16];
    __shared__ float lq[4][16];
    int w = threadIdx.x >> 6;
    int lane = threadIdx.x & 63;
    int r = lane & 15, quad = lane >> 4;
    int colbase = w * 64;

    bf16x8 bfr[4][8];
#pragma unroll
    for (int t = 0; t < 4; ++t)
#pragma unroll
        for (int kk = 0; kk < 8; ++kk)
            bfr[t][kk] = *(const bf16x8*)(Wt + (size_t)(colbase + t * 16 + r) * 256
                                          + kk * 32 + quad * 8);
    float bb[4], wA[4], wB[4];
#pragma unroll
    for (int t = 0; t < 4; ++t) {
        int col = colbase + t * 16 + r;
        if (w < 2) {
            bb[t] = 0.f;
            wA[t] = wp[col];
            wB[t] = wp[128 + col];
        } else {
            int c2 = col - 128;
            bb[t] = b2[c2];
            wA[t] = wp[c2];
            wB[t] = wp[128 + c2];
        }
    }

    for (int tile = blockIdx.x; tile < MTILES; tile += GEMM_GRID) {
        int m0 = tile * 16;
        int row = m0 + r;
        bf16x8 a[8];
#pragma unroll
        for (int kk = 0; kk < 8; ++kk)
            a[kk] = *(const bf16x8*)(h1b + (size_t)row * 256 + kk * 32 + quad * 8);
        floatx4 acc[4];
#pragma unroll
        for (int t = 0; t < 4; ++t) acc[t] = (floatx4){0.f, 0.f, 0.f, 0.f};
#pragma unroll
        for (int kk = 0; kk < 8; ++kk)
#pragma unroll
            for (int t = 0; t < 4; ++t)
                acc[t] = __builtin_amdgcn_mfma_f32_16x16x32_bf16(a[kk], bfr[t][kk],
                                                                 acc[t], 0, 0, 0);
        float pacc[4], qacc[4];
#pragma unroll
        for (int rr = 0; rr < 4; ++rr) {
            float pr = 0.f, qr = 0.f;
#pragma unroll
            for (int t = 0; t < 4; ++t) {
                float v = acc[t][rr] + bb[t];
                pr += v * wA[t];
                qr += v * wB[t];
            }
            pacc[rr] = pr;
            qacc[rr] = qr;
        }
#pragma unroll
        for (int m = 1; m <= 8; m <<= 1) {
#pragma unroll
            for (int rr = 0; rr < 4; ++rr) {
                pacc[rr] += __shfl_xor(pacc[rr], m);
                qacc[rr] += __shfl_xor(qacc[rr], m);
            }
        }
        if (r == 0) {
#pragma unroll
            for (int rr = 0; rr < 4; ++rr) {
                lp[w][quad * 4 + rr] = pacc[rr];
                lq[w][quad * 4 + rr] = qacc[rr];
            }
        }
        __syncthreads();
        if (threadIdx.x < 16) {
            int rw = threadIdx.x;
            float4 o;
            o.x = lp[0][rw] + lp[1][rw];
            o.y = lq[0][rw] + lq[1][rw];
            o.z = lp[2][rw] + lp[3][rw];
            o.w = lq[2][rw] + lq[3][rw];
            nodev[m0 + rw] = o;
        }
        __syncthreads();
    }
}

// scalar gather: p[n] = ps[n] + mean(zp[src]); q likewise. nodev is 800 KB.
__global__ __launch_bounds__(256) void gather2_kernel(
    const float4* __restrict__ nodev, const int* __restrict__ rowstart,
    const int* __restrict__ rowend, const int* __restrict__ csr,
    float* __restrict__ p, float* __restrict__ q) {
    int t = threadIdx.x;
    int node = blockIdx.x * 16 + (t >> 4);
    if (node >= NN) return;
    int l = t & 15;
    int beg = rowstart[node], end = rowend[node];
    float pz = 0.f, qz = 0.f;
    for (int i = beg + l; i < end; i += 16) {
        float4 v = nodev[csr[i]];
        pz += v.x;
        qz += v.y;
    }
#pragma unroll
    for (int m = 8; m >= 1; m >>= 1) {
        pz += __shfl_xor(pz, m);
        qz += __shfl_xor(qz, m);
    }
    if (l == 0) {
        int deg = end - beg;
        float inv = 1.0f / (float)(deg > 0 ? deg : 1);
        float4 me = nodev[node];
        p[node] = me.z + pz * inv;
        q[node] = me.w + qz * inv;
    }
}

__global__ __launch_bounds__(256) void score_kernel(
    const int* __restrict__ psrc, const int* __restrict__ pdst,
    const int* __restrict__ nsrc, const int* __restrict__ ndst,
    const float* __restrict__ p, const float* __restrict__ q,
    const float* __restrict__ bp, float* __restrict__ out) {
    int i = blockIdx.x * blockDim.x + threadIdx.x;
    float b = bp[0];
    if (i < EPOS) {
        out[i] = p[psrc[i]] + q[pdst[i]] + b;
    } else if (i < EPOS + ENEG) {
        int j = i - EPOS;
        out[i] = p[nsrc[j]] + q[ndst[j]] + b;
    }
}

extern "C" void kernel_launch(void* const* d_in, const int* in_sizes, int n_in,
                              void* d_out, int out_size, void* d_ws, size_t ws_size,
                              hipStream_t stream) {
    const float* x    = (const float*)d_in[0];
    const int*   msrc = (const int*)d_in[1];
    const int*   mdst = (const int*)d_in[2];
    const int*   psrc = (const int*)d_in[3];
    const int*   pdst = (const int*)d_in[4];
    const int*   nsrc = (const int*)d_in[5];
    const int*   ndst = (const int*)d_in[6];
    const float* W1s  = (const float*)d_in[7];
    const float* W1n  = (const float*)d_in[8];
    const float* b1   = (const float*)d_in[9];
    const float* W2s  = (const float*)d_in[10];
    const float* W2n  = (const float*)d_in[11];
    const float* b2   = (const float*)d_in[12];
    const float* wp   = (const float*)d_in[13];
    const float* bp   = (const float*)d_in[14];

    char* ws = (char*)d_ws;
    int*   cntM     = (int*)ws + I_CNT;
    int*   offM     = (int*)ws + I_OFF;
    int*   rowstart = (int*)ws + I_ROW;
    int*   rowend   = (int*)ws + I_REND;
    int*   csr      = (int*)ws + I_CSR;
    unsigned* creg  = (unsigned*)(ws + B_CREG);
    bf16*  xb    = (bf16*)(ws + B_XB);
    bf16*  agg1b = (bf16*)(ws + B_AGG1);
    bf16*  h1b   = (bf16*)(ws + B_H1);
    float4* nodev = (float4*)(ws + B_NV);
    bf16*  Wt1   = (bf16*)(ws + B_WT1);
    bf16*  Wt2   = (bf16*)(ws + B_WT2);
    float* p     = (float*)(ws + B_P);
    float* q     = (float*)(ws + B_Q);
    float* out   = (float*)d_out;

    convbin_kernel<<<XCONV + 256 + CBLK, 256, 0, stream>>>(
        x, xb, W1s, W1n, W2n, W2s, Wt1, Wt2, msrc, mdst, creg, cntM, offM);
    bucket_kernel<<<NB, BT, 0, stream>>>(creg, cntM, offM, rowstart, rowend,
                                         csr, xb, agg1b);
    gemm1_kernel<<<GEMM_GRID, 256, 0, stream>>>(xb, agg1b, Wt1, b1, h1b);
    gemm2_kernel<<<GEMM_GRID, 256, 0, stream>>>(h1b, Wt2, b2, wp, nodev);
    gather2_kernel<<<(NN + 15) / 16, 256, 0, stream>>>(nodev, rowstart, rowend, csr, p, q);
    score_kernel<<<(EPOS + ENEG + 255) / 256, 256, 0, stream>>>(
        psrc, pdst, nsrc, ndst, p, q, bp, out);
}